// Round 16
// baseline (22.129 us; speedup 1.0000x reference)
//
#include <hip/hip_runtime.h>
#include <stdint.h>

#define NB 64      // batch rows
#define NK 1024    // keys
#define ND 512     // dim
#define ROWS 2                                  // batch rows per block
#define CHUNKS 32                               // key chunks
#define KPB (NK / CHUNKS)                       // 32 keys per block
#define WPB 4                                   // waves per block
#define KPW (KPB / WPB)                         // 8 keys per wave
#define NCOMBO (ROWS * KPW)                     // 16 (row,key) combos per wave
// ws layout: u64 packed winner per (row, chunk): [NB][CHUNKS]

typedef float v2f __attribute__((ext_vector_type(2)));

#if __has_builtin(__builtin_amdgcn_exp2f)
#define EXP2F(x) __builtin_amdgcn_exp2f(x)
#else
#define EXP2F(x) exp2f(x)
#endif
#if __has_builtin(__builtin_amdgcn_rcpf)
#define RCPF(x) __builtin_amdgcn_rcpf(x)
#else
#define RCPF(x) (1.0f / (x))
#endif

// Packed silu pair with shared reciprocal (R15-proven):
//   u = qc*kv; y = -(u+1)*log2e; e = exp2(y); f = 1+e
//   r = rcp(f.x*f.y); sig = (r*f.y, r*f.x); acc += u*sig
// Mask dropped (R13-proven): zero key elems give exactly-zero terms; sub-1e-6
// elems perturb scores ~1e-5 << top-2 gaps -> argmax-invariant.
__device__ __forceinline__ void silu2_acc(v2f qc, v2f kv, v2f& acc) {
    const float NL2E = -1.4426950408889634f;
    v2f u = qc * kv;
    v2f y = u * NL2E + NL2E;
    v2f e;
    e.x = EXP2F(y.x);
    e.y = EXP2F(y.y);
    v2f f = e + 1.0f;
    float r = RCPF(f.x * f.y);
    v2f sg;
    sg.x = r * f.y;
    sg.y = r * f.x;
    acc += u * sg;
}

// pack: [sortable_score:32][..][1023-k:10]. max() picks best score; on exact
// score ties larger (1023-k) => smaller k wins (numpy argmax first-occurrence).
__device__ __forceinline__ unsigned long long pack_win(float s, int k) {
    uint32_t bits = __float_as_uint(s);
    uint32_t so = (bits & 0x80000000u) ? ~bits : (bits | 0x80000000u);
    return ((unsigned long long)so << 32) | (unsigned long long)(uint32_t)(NK - 1 - k);
}

__global__ __launch_bounds__(256, 4) void sia_scores(const float* __restrict__ q,
                                                     const float* __restrict__ keys,
                                                     unsigned long long* __restrict__ ws) {
    const int bidx = blockIdx.x;            // 0 .. 1023
    const int bg    = bidx >> 5;            // row group 0..31
    const int chunk = bidx & (CHUNKS - 1);  // 0..31
    const int tid = threadIdx.x;
    const int wave = tid >> 6;
    const int lane = tid & 63;

    const float C = 100.0f * 0.04419417382415922f;   // SCALE * D^-0.5

    // 2 rows' q fragments as 4 v2f each; lane owns dims [lane*8, lane*8+8)
    v2f qv[ROWS][4];
    #pragma unroll
    for (int r = 0; r < ROWS; ++r) {
        const v2f* q2 = reinterpret_cast<const v2f*>(q + (bg * ROWS + r) * ND + lane * 8);
        #pragma unroll
        for (int j = 0; j < 4; ++j)
            qv[r][j] = q2[j] * C;
    }

    const int k0 = chunk * KPB + wave * KPW;

    v2f acc[ROWS][KPW];
    #pragma unroll
    for (int r = 0; r < ROWS; ++r)
        #pragma unroll
        for (int i = 0; i < KPW; ++i)
            acc[r][i] = (v2f)0.0f;

    #pragma unroll
    for (int i = 0; i < KPW; ++i) {
        const float4* k4 = reinterpret_cast<const float4*>(keys + (k0 + i) * ND + lane * 8);
        float4 ka = k4[0];
        float4 kb = k4[1];
        v2f kv[4];
        kv[0] = (v2f){ka.x, ka.y};
        kv[1] = (v2f){ka.z, ka.w};
        kv[2] = (v2f){kb.x, kb.y};
        kv[3] = (v2f){kb.z, kb.w};
        #pragma unroll
        for (int r = 0; r < ROWS; ++r)
            #pragma unroll
            for (int j = 0; j < 4; ++j)
                silu2_acc(qv[r][j], kv[j], acc[r][i]);
    }

    // collapse v2f halves; combo index c = r*KPW + i
    float val[NCOMBO];
    #pragma unroll
    for (int r = 0; r < ROWS; ++r)
        #pragma unroll
        for (int i = 0; i < KPW; ++i)
            val[r * KPW + i] = acc[r][i].x + acc[r][i].y;

    // Reduce-scatter fold over lane-bits 32,16,8,4: halve the live array each
    // step (15 shfl+add total). Fold order 32,16,8,4 then finish 2,1 — the
    // SAME xor-tree order as the R15 all-to-all butterfly -> bit-identical sums.
    #pragma unroll
    for (int b = 32, h = NCOMBO / 2; b >= 4; b >>= 1, h >>= 1) {
        #pragma unroll
        for (int i = 0; i < h; ++i) {
            float send = (lane & b) ? val[i] : val[i + h];
            float recv = __shfl_xor(send, b, 64);
            float keep = (lane & b) ? val[i + h] : val[i];
            val[i] = keep + recv;
        }
    }
    float v = val[0];
    v += __shfl_xor(v, 2, 64);
    v += __shfl_xor(v, 1, 64);
    // lane now holds the full score of combo: r = lane bit5, j = (lane>>2)&7

    const int j = (lane >> 2) & 7;
    unsigned long long p = pack_win(v, k0 + j);

    // parallel argmax: fold replica bits {1,2} and key bits {4,8,16};
    // bit 32 (row) stays unfolded -> lane 0 = row 0 winner, lane 32 = row 1.
    #pragma unroll
    for (int o = 16; o >= 1; o >>= 1) {
        unsigned long long t = __shfl_xor(p, o, 64);
        if (t > p) p = t;
    }

    __shared__ unsigned long long win[WPB][ROWS];
    if (lane == 0)  win[wave][0] = p;
    if (lane == 32) win[wave][1] = p;
    __syncthreads();

    // cross-wave reduce (packed max also resolves index ties to smaller k)
    if (tid < ROWS) {
        const int r = tid;
        unsigned long long w = win[0][r];
        #pragma unroll
        for (int ww = 1; ww < WPB; ++ww)
            if (win[ww][r] > w) w = win[ww][r];
        ws[(bg * ROWS + r) * CHUNKS + chunk] = w;
    }
}

__global__ __launch_bounds__(128) void sia_final(const unsigned long long* __restrict__ ws,
                                                 const float* __restrict__ values,
                                                 float* __restrict__ out) {
    const int b = blockIdx.x;
    const int tid = threadIdx.x;
    const int lane = tid & 63;

    // 32 chunk winners; lanes 32-63 duplicate (harmless under max)
    unsigned long long p = ws[b * CHUNKS + (lane & 31)];
    #pragma unroll
    for (int o = 16; o >= 1; o >>= 1) {
        unsigned long long t = __shfl_xor(p, o, 64);
        if (t > p) p = t;
    }
    const int k = NK - 1 - (int)((uint32_t)p & 0x3FFu);

    // gather winner's values row: 128 threads x 16B = 2KB
    const float4* v4 = reinterpret_cast<const float4*>(values + (size_t)k * ND);
    float4* o4 = reinterpret_cast<float4*>(out + b * ND);
    o4[tid] = v4[tid];

    if (tid == 0)
        out[NB * ND + b] = (float)k;   // winner_idx, read back as float32
}

extern "C" void kernel_launch(void* const* d_in, const int* in_sizes, int n_in,
                              void* d_out, int out_size, void* d_ws, size_t ws_size,
                              hipStream_t stream) {
    const float* q      = (const float*)d_in[0];   // [64, 512]
    const float* keys   = (const float*)d_in[1];   // [1024, 512]
    const float* values = (const float*)d_in[2];   // [1024, 512]
    float* out = (float*)d_out;                    // 64*512 values then 64 idx
    unsigned long long* ws = (unsigned long long*)d_ws;

    sia_scores<<<dim3((NB / ROWS) * CHUNKS), dim3(256), 0, stream>>>(q, keys, ws);
    sia_final<<<dim3(NB), dim3(128), 0, stream>>>(ws, values, out);
}

// Round 17
// 16.252 us; speedup vs baseline: 1.3616x; 1.3616x over previous
//
#include <hip/hip_runtime.h>
#include <stdint.h>

#define NB 64      // batch rows
#define NK 1024    // keys
#define ND 512     // dim
#define ROWS 2                                  // batch rows per block
#define CHUNKS 64                               // key chunks
#define KPB (NK / CHUNKS)                       // 16 keys per block
#define WPB 4                                   // waves per block
// wave: 4 groups x 16 lanes; group g owns key k0+g; lane s owns dims {j*64+s*4}
// ws layout: u64 packed winner per (row, chunk): [NB][CHUNKS]

typedef float v2f __attribute__((ext_vector_type(2)));

#if __has_builtin(__builtin_amdgcn_exp2f)
#define EXP2F(x) __builtin_amdgcn_exp2f(x)
#else
#define EXP2F(x) exp2f(x)
#endif
#if __has_builtin(__builtin_amdgcn_rcpf)
#define RCPF(x) __builtin_amdgcn_rcpf(x)
#else
#define RCPF(x) (1.0f / (x))
#endif

// Packed silu pair with shared reciprocal (R15-proven):
//   u = qc*kv; y = -(u+1)*log2e; e = exp2(y); f = 1+e
//   r = rcp(f.x*f.y); sig = (r*f.y, r*f.x); acc += u*sig
// Mask dropped (R13-proven): zero key elems give exactly-zero terms; sub-1e-6
// elems perturb scores ~1e-5 << top-2 gaps -> argmax-invariant.
__device__ __forceinline__ void silu2_acc(v2f qc, v2f kv, v2f& acc) {
    const float NL2E = -1.4426950408889634f;
    v2f u = qc * kv;
    v2f y = u * NL2E + NL2E;
    v2f e;
    e.x = EXP2F(y.x);
    e.y = EXP2F(y.y);
    v2f f = e + 1.0f;
    float r = RCPF(f.x * f.y);
    v2f sg;
    sg.x = r * f.y;
    sg.y = r * f.x;
    acc += u * sg;
}

// pack: [sortable_score:32][..][1023-k:10]. max() picks best score; on exact
// score ties larger (1023-k) => smaller k wins (numpy argmax first-occurrence).
__device__ __forceinline__ unsigned long long pack_win(float s, int k) {
    uint32_t bits = __float_as_uint(s);
    uint32_t so = (bits & 0x80000000u) ? ~bits : (bits | 0x80000000u);
    return ((unsigned long long)so << 32) | (unsigned long long)(uint32_t)(NK - 1 - k);
}

__global__ __launch_bounds__(256, 4) void sia_scores(const float* __restrict__ q,
                                                     const float* __restrict__ keys,
                                                     unsigned long long* __restrict__ ws) {
    const int bidx = blockIdx.x;            // 0 .. 2047
    const int bg    = bidx >> 6;            // row group 0..31
    const int chunk = bidx & (CHUNKS - 1);  // 0..63
    const int tid = threadIdx.x;
    const int wave = tid >> 6;
    const int lane = tid & 63;
    const int s = lane & 15;                // sub-lane within 16-lane group

    const float C = 100.0f * 0.04419417382415922f;   // SCALE * D^-0.5

    const int k0 = chunk * KPB + wave * 4;  // this wave's 4 keys
    const int kg = k0 + ((lane >> 4) & 3);  // this group's key

    // q fragments: row r, float4 at dim j*64 + s*4 (duplicated across groups)
    float4 qv[ROWS][8];
    #pragma unroll
    for (int r = 0; r < ROWS; ++r) {
        const float4* q4 = reinterpret_cast<const float4*>(q + (bg * ROWS + r) * ND) + s;
        #pragma unroll
        for (int j = 0; j < 8; ++j) {
            float4 t = q4[j * 16];
            t.x *= C; t.y *= C; t.z *= C; t.w *= C;
            qv[r][j] = t;
        }
    }

    // accumulate 32 dims/lane for this group's key, both rows (2 acc chains/row)
    const float4* kp = reinterpret_cast<const float4*>(keys + (size_t)kg * ND) + s;
    v2f acc0[ROWS] = {(v2f)0.0f, (v2f)0.0f};
    v2f acc1[ROWS] = {(v2f)0.0f, (v2f)0.0f};
    #pragma unroll
    for (int j = 0; j < 8; ++j) {
        float4 kv = kp[j * 16];
        v2f klo = (v2f){kv.x, kv.y};
        v2f khi = (v2f){kv.z, kv.w};
        #pragma unroll
        for (int r = 0; r < ROWS; ++r) {
            silu2_acc((v2f){qv[r][j].x, qv[r][j].y}, klo, acc0[r]);
            silu2_acc((v2f){qv[r][j].z, qv[r][j].w}, khi, acc1[r]);
        }
    }

    // pack both rows' partials into one v2f, butterfly within the 16-lane group
    v2f sc;
    sc.x = (acc0[0].x + acc0[0].y) + (acc1[0].x + acc1[0].y);
    sc.y = (acc0[1].x + acc0[1].y) + (acc1[1].x + acc1[1].y);
    #pragma unroll
    for (int off = 8; off >= 1; off >>= 1) {
        v2f o;
        o.x = __shfl_xor(sc.x, off, 64);
        o.y = __shfl_xor(sc.y, off, 64);
        sc += o;
    }
    // every lane of the group now holds both rows' full scores for key kg

    unsigned long long p0 = pack_win(sc.x, kg);
    unsigned long long p1 = pack_win(sc.y, kg);
    // argmax across the 4 groups (lane bits 4,5)
    #pragma unroll
    for (int off = 16; off <= 32; off <<= 1) {
        unsigned long long t0 = __shfl_xor(p0, off, 64);
        unsigned long long t1 = __shfl_xor(p1, off, 64);
        if (t0 > p0) p0 = t0;
        if (t1 > p1) p1 = t1;
    }

    __shared__ unsigned long long win[WPB][ROWS];
    if (lane == 0) { win[wave][0] = p0; win[wave][1] = p1; }
    __syncthreads();

    // cross-wave reduce (packed max also resolves index ties to smaller k)
    if (tid < ROWS) {
        const int r = tid;
        unsigned long long w = win[0][r];
        #pragma unroll
        for (int ww = 1; ww < WPB; ++ww)
            if (win[ww][r] > w) w = win[ww][r];
        ws[(bg * ROWS + r) * CHUNKS + chunk] = w;
    }
}

__global__ __launch_bounds__(128) void sia_final(const unsigned long long* __restrict__ ws,
                                                 const float* __restrict__ values,
                                                 float* __restrict__ out) {
    const int b = blockIdx.x;
    const int tid = threadIdx.x;
    const int lane = tid & 63;

    // both waves redundantly reduce (avoids a barrier)
    unsigned long long p = ws[b * CHUNKS + lane];
    #pragma unroll
    for (int off = 32; off > 0; off >>= 1) {
        unsigned long long o = __shfl_xor(p, off, 64);
        if (o > p) p = o;
    }
    const int k = NK - 1 - (int)((uint32_t)p & 0x3FFu);

    // gather winner's values row: 128 threads x 16B = 2KB
    const float4* v4 = reinterpret_cast<const float4*>(values + (size_t)k * ND);
    float4* o4 = reinterpret_cast<float4*>(out + b * ND);
    o4[tid] = v4[tid];

    if (tid == 0)
        out[NB * ND + b] = (float)k;   // winner_idx, read back as float32
}

extern "C" void kernel_launch(void* const* d_in, const int* in_sizes, int n_in,
                              void* d_out, int out_size, void* d_ws, size_t ws_size,
                              hipStream_t stream) {
    const float* q      = (const float*)d_in[0];   // [64, 512]
    const float* keys   = (const float*)d_in[1];   // [1024, 512]
    const float* values = (const float*)d_in[2];   // [1024, 512]
    float* out = (float*)d_out;                    // 64*512 values then 64 idx
    unsigned long long* ws = (unsigned long long*)d_ws;

    sia_scores<<<dim3((NB / ROWS) * CHUNKS), dim3(256), 0, stream>>>(q, keys, ws);
    sia_final<<<dim3(NB), dim3(128), 0, stream>>>(ws, values, out);
}